// Round 9
// baseline (101.596 us; speedup 1.0000x reference)
//
#include <hip/hip_runtime.h>
#include <math.h>

typedef __attribute__((ext_vector_type(8))) short short8v;   // 8 bf16 bits
typedef __attribute__((ext_vector_type(4))) float f32x4;     // 16x16 MFMA acc

__device__ __forceinline__ unsigned short f2bf(float x) {
    union { float f; unsigned u; } v; v.f = x;
    unsigned r = v.u + 0x7FFF + ((v.u >> 16) & 1);   // RNE
    return (unsigned short)(r >> 16);
}
__device__ __forceinline__ float bf2f(unsigned short u) {
    union { unsigned u; float f; } v; v.u = ((unsigned)u) << 16;
    return v.f;
}
__device__ __forceinline__ unsigned pack2bf(float a, float b) {
    return (unsigned)f2bf(a) | ((unsigned)f2bf(b) << 16);
}
__device__ __forceinline__ float fast_tanh(float x) {
    float e = __expf(2.0f * x);
    return 1.0f - 2.0f / (e + 1.0f);
}
__device__ __host__ __forceinline__ int sigma_perm(int ct, int p) {
    return 32 * (ct >> 1) + 8 * (p >> 2) + 4 * (ct & 1) + (p & 3);
}

// d_ws layout (bytes):
//   [0, 4096)       A     f32  [64][16]
//   [4096, 12288)   W1P   bf16 [8 ct][16 row][32 k]  k>=16 ZERO, sigma rows
//   [12288, 45056)  W2P   bf16 [8 ct][16 row][128 k] sigma rows
//   [45056, 49152)  W3T   bf16 [16 col][128 k]
//   [49152, 49152 + B*64)  LS buffer f32 [B][16]   (two-kernel path only)
#define WS_A    0
#define WS_W1   4096
#define WS_W2   12288
#define WS_W3   45056
#define WS_LS   49152

// ---------------------------------------------------------------------------
// Prep (proven): one block, 256 threads.
// ---------------------------------------------------------------------------
__global__ __launch_bounds__(256) void ce_prep_kernel(
    const int* __restrict__ pilot_pos,
    const float* __restrict__ decay_param,
    const float* __restrict__ window_logits,
    const float* __restrict__ W1, const float* __restrict__ W2,
    const float* __restrict__ W3,
    char* __restrict__ ws)
{
    __shared__ float win[8], Gr[64], Gi[64], wln[64], wrn[64];
    __shared__ int lefts[64], pos[8];
    int t = threadIdx.x;
    if (t < 8) {
        pos[t] = pilot_pos[t];
        win[t] = 1.0f / (1.0f + expf(-window_logits[t]));
    }
    __syncthreads();
    float decay = log1pf(expf(decay_param[0]));
    if (t < 64) {
        float gr = 0.f, gi = 0.f;
        #pragma unroll
        for (int n = 0; n < 8; ++n) {
            float ang = 6.283185307179586f * (float)(n * t) * (1.0f / 64.0f);
            gr += win[n] * cosf(ang);
            gi += win[n] * sinf(ang);
        }
        Gr[t] = gr * (1.0f / 64.0f);
        Gi[t] = gi * (1.0f / 64.0f);
        int lft = 0;
        #pragma unroll
        for (int p = 1; p < 8; ++p) if (pos[p] <= t) lft = p;
        if (lft > 6) lft = 6;
        float x0 = (float)pos[lft], x1 = (float)pos[lft + 1], fi = (float)t;
        float wl = expf(-decay * fabsf(fi - x0));
        float wr = expf(-decay * fabsf(x1 - fi));
        float wsum = wl + wr + 1e-12f;
        lefts[t] = lft; wln[t] = wl / wsum; wrn[t] = wr / wsum;
    }
    __syncthreads();
    if (t < 64) {
        float ar[8], ai[8];
        for (int p = 0; p < 8; ++p) { ar[p] = 0.f; ai[p] = 0.f; }
        for (int i = 0; i < 64; ++i) {
            int d = (i - t) & 63;
            float gr = Gr[d], gi = Gi[d];
            int lft = lefts[i];
            float wa = wln[i], wb = wrn[i];
            ar[lft]     += wa * gr;  ai[lft]     += wa * gi;
            ar[lft + 1] += wb * gr;  ai[lft + 1] += wb * gi;
        }
        float* A = (float*)(ws + WS_A);
        for (int p = 0; p < 8; ++p) {
            A[t * 16 + 2 * p]     = ar[p];
            A[t * 16 + 2 * p + 1] = ai[p];
        }
    }
    unsigned short* w1p = (unsigned short*)(ws + WS_W1);
    for (int i = t; i < 128 * 32; i += 256) {
        int row = i >> 5, k = i & 31;
        int ct = row >> 4, p = row & 15;
        w1p[i] = (k < 16) ? f2bf(W1[k * 128 + sigma_perm(ct, p)]) : (unsigned short)0;
    }
    unsigned short* w2p = (unsigned short*)(ws + WS_W2);
    for (int i = t; i < 128 * 128; i += 256) {
        int row = i >> 7, k = i & 127;
        int ct = row >> 4, p = row & 15;
        w2p[i] = f2bf(W2[k * 128 + sigma_perm(ct, p)]);
    }
    unsigned short* w3t = (unsigned short*)(ws + WS_W3);
    for (int i = t; i < 16 * 128; i += 256) {
        int col = i >> 7, k = i & 127;
        w3t[i] = f2bf(W3[k * 64 + col]);
    }
}

// ---------------------------------------------------------------------------
// Kernel A: LS gather. 1 thread per element; 8 scattered Y reads + Xp,
// writes ls[16] f32 coalesced (64 B/thread, 4 KB/wave).
// ---------------------------------------------------------------------------
__global__ __launch_bounds__(256) void ce_ls(
    const float* __restrict__ Y, const float* __restrict__ Xp,
    const int* __restrict__ pilot_pos,
    float* __restrict__ lsbuf, int B)
{
    long e = (long)blockIdx.x * 256 + threadIdx.x;
    if (e >= B) return;
    const float* yrow = Y + e * 128;
    const float4* xr = (const float4*)(Xp + e * 16);
    float4 x0 = xr[0], x1 = xr[1], x2 = xr[2], x3 = xr[3];
    float c[8] = { x0.x, x0.z, x1.x, x1.z, x2.x, x2.z, x3.x, x3.z };
    float d[8] = { x0.y, x0.w, x1.y, x1.w, x2.y, x2.w, x3.y, x3.w };
    float2 y[8];
    #pragma unroll
    for (int p = 0; p < 8; ++p) y[p] = *(const float2*)(yrow + pilot_pos[p] * 2);
    float o[16];
    #pragma unroll
    for (int p = 0; p < 8; ++p) {
        float inv = 1.0f / (c[p] * c[p] + d[p] * d[p]);
        o[2 * p]     = (y[p].x * c[p] + y[p].y * d[p]) * inv;
        o[2 * p + 1] = (y[p].y * c[p] - y[p].x * d[p]) * inv;
    }
    float* op = lsbuf + e * 16;
    #pragma unroll
    for (int q = 0; q < 4; ++q) {
        float4 st = { o[4 * q], o[4 * q + 1], o[4 * q + 2], o[4 * q + 3] };
        *(float4*)(op + 4 * q) = st;
    }
}

// ---------------------------------------------------------------------------
// Kernel B: register-resident MLP (R8-proven) with coalesced ls input.
// 256 thr = 4 waves, 16 elems/wave.
// ---------------------------------------------------------------------------
__global__ __launch_bounds__(256) void ce_mlp(
    const float* __restrict__ lsbuf,
    const float* __restrict__ b1, const float* __restrict__ b2,
    const float* __restrict__ b3,
    const float* __restrict__ est_w, const float* __restrict__ alpha,
    const char* __restrict__ ws,
    float* __restrict__ out, int B)
{
    __shared__ float sLS[64 * 16];
    __shared__ unsigned short sO[64 * 16];

    const unsigned short* w1p = (const unsigned short*)(ws + WS_W1);
    const unsigned short* w2p = (const unsigned short*)(ws + WS_W2);
    const unsigned short* w3t = (const unsigned short*)(ws + WS_W3);
    const float* Amat = (const float*)(ws + WS_A);

    const int t = threadIdx.x;
    const int w = t >> 6, l = t & 63;
    const int m = l & 15, kg = l >> 4;
    const int e_loc = w * 16 + m;
    long eg = (long)blockIdx.x * 64 + e_loc;
    long egc = (eg < B) ? eg : (long)(B - 1);

    // ---- coalesced ls input ----
    short8v xb = {0, 0, 0, 0, 0, 0, 0, 0};
    if (kg < 2) {
        const float4* lp = (const float4*)(lsbuf + egc * 16 + kg * 8);
        float4 s0 = lp[0], s1 = lp[1];
        *(float4*)(sLS + e_loc * 16 + kg * 8)     = s0;
        *(float4*)(sLS + e_loc * 16 + kg * 8 + 4) = s1;
        xb[0] = (short)f2bf(s0.x); xb[1] = (short)f2bf(s0.y);
        xb[2] = (short)f2bf(s0.z); xb[3] = (short)f2bf(s0.w);
        xb[4] = (short)f2bf(s1.x); xb[5] = (short)f2bf(s1.y);
        xb[6] = (short)f2bf(s1.z); xb[7] = (short)f2bf(s1.w);
    }

    const f32x4 z4 = {0.f, 0.f, 0.f, 0.f};
    typedef union { unsigned u[4]; short8v v; } pk_t;

    // ---- Layer 1 (8 MFMA) + repack ----
    pk_t h1[4];
    #pragma unroll
    for (int ks = 0; ks < 4; ++ks) {
        #pragma unroll
        for (int half = 0; half < 2; ++half) {
            int ct = 2 * ks + half;
            short8v wf = *(const short8v*)(w1p + (ct * 16 + m) * 32 + kg * 8);
            f32x4 acc = __builtin_amdgcn_mfma_f32_16x16x32_bf16(wf, xb, z4, 0, 0, 0);
            float4 bv = *(const float4*)(b1 + ks * 32 + kg * 8 + half * 4);
            float v0 = fmaxf(acc[0] + bv.x, 0.f), v1 = fmaxf(acc[1] + bv.y, 0.f);
            float v2 = fmaxf(acc[2] + bv.z, 0.f), v3 = fmaxf(acc[3] + bv.w, 0.f);
            h1[ks].u[2 * half]     = pack2bf(v0, v1);
            h1[ks].u[2 * half + 1] = pack2bf(v2, v3);
        }
    }

    // ---- Layer 2 (32 MFMA) ----
    f32x4 acc2[8];
    #pragma unroll
    for (int ct = 0; ct < 8; ++ct) acc2[ct] = z4;
    #pragma unroll
    for (int ks = 0; ks < 4; ++ks) {
        short8v hf = h1[ks].v;
        #pragma unroll
        for (int ct = 0; ct < 8; ++ct) {
            short8v wf = *(const short8v*)(w2p + (ct * 16 + m) * 128 + ks * 32 + kg * 8);
            acc2[ct] = __builtin_amdgcn_mfma_f32_16x16x32_bf16(wf, hf, acc2[ct], 0, 0, 0);
        }
    }

    // ---- repack -> h2 ----
    pk_t h2[4];
    #pragma unroll
    for (int ks = 0; ks < 4; ++ks) {
        #pragma unroll
        for (int half = 0; half < 2; ++half) {
            int ct = 2 * ks + half;
            float4 bv = *(const float4*)(b2 + ks * 32 + kg * 8 + half * 4);
            float v0 = fmaxf(acc2[ct][0] + bv.x, 0.f), v1 = fmaxf(acc2[ct][1] + bv.y, 0.f);
            float v2 = fmaxf(acc2[ct][2] + bv.z, 0.f), v3 = fmaxf(acc2[ct][3] + bv.w, 0.f);
            h2[ks].u[2 * half]     = pack2bf(v0, v1);
            h2[ks].u[2 * half + 1] = pack2bf(v2, v3);
        }
    }

    // ---- Layer 3 (4 MFMA) ----
    f32x4 acc3 = z4;
    #pragma unroll
    for (int ks = 0; ks < 4; ++ks) {
        short8v wf = *(const short8v*)(w3t + m * 128 + ks * 32 + kg * 8);
        acc3 = __builtin_amdgcn_mfma_f32_16x16x32_bf16(wf, h2[ks].v, acc3, 0, 0, 0);
    }
    {
        uint2 u = { pack2bf(acc3[0], acc3[1]), pack2bf(acc3[2], acc3[3]) };
        *(uint2*)(sO + e_loc * 16 + kg * 4) = u;
    }
    __syncthreads();

    // ---- comb ----
    float w0 = est_w[0];
    float al = fminf(fmaxf(alpha[0], 0.f), 1.f);
    float oma = 1.0f - al;
    {
        int e2 = t >> 2, q = t & 3;
        float* lsp = sLS + e2 * 16 + q * 4;
        float4 lv = *(float4*)lsp;
        const unsigned short* op = sO + e2 * 16;
        float or0 = bf2f(op[2 * q])     + b3[2 * q];
        float or1 = bf2f(op[2 * q + 1]) + b3[2 * q + 1];
        float oi0 = bf2f(op[8 + 2 * q]) + b3[8 + 2 * q];
        float oi1 = bf2f(op[9 + 2 * q]) + b3[9 + 2 * q];
        float4 cb;
        cb.x = al * (lv.x * w0) + oma * fast_tanh(or0);
        cb.y = al * (lv.y * w0) + oma * fast_tanh(oi0);
        cb.z = al * (lv.z * w0) + oma * fast_tanh(or1);
        cb.w = al * (lv.w * w0) + oma * fast_tanh(oi1);
        *(float4*)lsp = cb;
    }
    __syncthreads();

    // ---- epilogue: 1 KB contiguous per wave-instr ----
    {
        int j = l & 31, half = l >> 5;
        float Ar[32];
        const float4* ap = (const float4*)(Amat + j * 32);
        #pragma unroll
        for (int q4 = 0; q4 < 8; ++q4) {
            float4 v = ap[q4];
            Ar[4 * q4 + 0] = v.x; Ar[4 * q4 + 1] = v.y;
            Ar[4 * q4 + 2] = v.z; Ar[4 * q4 + 3] = v.w;
        }
        #pragma unroll
        for (int it = 0; it < 8; ++it) {
            int e2 = w * 16 + 2 * it + half;
            long gelem = (long)blockIdx.x * 64 + e2;
            const float* lsp = sLS + e2 * 16;
            float4 C0 = *(const float4*)(lsp + 0), C1 = *(const float4*)(lsp + 4);
            float4 C2 = *(const float4*)(lsp + 8), C3 = *(const float4*)(lsp + 12);
            float cr[8] = { C0.x, C0.z, C1.x, C1.z, C2.x, C2.z, C3.x, C3.z };
            float ci[8] = { C0.y, C0.w, C1.y, C1.w, C2.y, C2.w, C3.y, C3.w };
            float hr0 = 0.f, hi0 = 0.f, hr1 = 0.f, hi1 = 0.f;
            #pragma unroll
            for (int p = 0; p < 8; ++p) {
                float a0r = Ar[2 * p], a0i = Ar[2 * p + 1];
                float a1r = Ar[16 + 2 * p], a1i = Ar[17 + 2 * p];
                hr0 += cr[p] * a0r - ci[p] * a0i;
                hi0 += cr[p] * a0i + ci[p] * a0r;
                hr1 += cr[p] * a1r - ci[p] * a1i;
                hi1 += cr[p] * a1i + ci[p] * a1r;
            }
            if (gelem < B) {
                float4 st = { hr0, hi0, hr1, hi1 };
                *(float4*)(out + gelem * 128 + j * 4) = st;
            }
        }
    }
}

// ---------------------------------------------------------------------------
// Fallback single kernel (R8, passed at 93.8 us) for small ws_size.
// ---------------------------------------------------------------------------
__global__ __launch_bounds__(256) void ce_main_fb(
    const float* __restrict__ Y, const float* __restrict__ Xp,
    const int* __restrict__ pilot_pos,
    const float* __restrict__ b1, const float* __restrict__ b2,
    const float* __restrict__ b3,
    const float* __restrict__ est_w, const float* __restrict__ alpha,
    const char* __restrict__ ws,
    float* __restrict__ out, int B)
{
    __shared__ float sLS[64 * 16];
    __shared__ unsigned short sO[64 * 16];
    const unsigned short* w1p = (const unsigned short*)(ws + WS_W1);
    const unsigned short* w2p = (const unsigned short*)(ws + WS_W2);
    const unsigned short* w3t = (const unsigned short*)(ws + WS_W3);
    const float* Amat = (const float*)(ws + WS_A);
    const int t = threadIdx.x;
    const int w = t >> 6, l = t & 63;
    const int m = l & 15, kg = l >> 4;
    const int e_loc = w * 16 + m;
    long eg = (long)blockIdx.x * 64 + e_loc;
    long egc = (eg < B) ? eg : (long)(B - 1);
    short8v xb = {0, 0, 0, 0, 0, 0, 0, 0};
    if (kg < 2) {
        const float* yrow = Y + egc * 128;
        const float4* xr = (const float4*)(Xp + egc * 16 + kg * 8);
        float4 x0 = xr[0], x1 = xr[1];
        int p0 = kg * 4;
        float2 y0 = *(const float2*)(yrow + pilot_pos[p0 + 0] * 2);
        float2 y1 = *(const float2*)(yrow + pilot_pos[p0 + 1] * 2);
        float2 y2 = *(const float2*)(yrow + pilot_pos[p0 + 2] * 2);
        float2 y3 = *(const float2*)(yrow + pilot_pos[p0 + 3] * 2);
        float ls[8], inv;
        inv = 1.0f / (x0.x * x0.x + x0.y * x0.y);
        ls[0] = (y0.x * x0.x + y0.y * x0.y) * inv;
        ls[1] = (y0.y * x0.x - y0.x * x0.y) * inv;
        inv = 1.0f / (x0.z * x0.z + x0.w * x0.w);
        ls[2] = (y1.x * x0.z + y1.y * x0.w) * inv;
        ls[3] = (y1.y * x0.z - y1.x * x0.w) * inv;
        inv = 1.0f / (x1.x * x1.x + x1.y * x1.y);
        ls[4] = (y2.x * x1.x + y2.y * x1.y) * inv;
        ls[5] = (y2.y * x1.x - y2.x * x1.y) * inv;
        inv = 1.0f / (x1.z * x1.z + x1.w * x1.w);
        ls[6] = (y3.x * x1.z + y3.y * x1.w) * inv;
        ls[7] = (y3.y * x1.z - y3.x * x1.w) * inv;
        float4 s0 = { ls[0], ls[1], ls[2], ls[3] };
        float4 s1 = { ls[4], ls[5], ls[6], ls[7] };
        *(float4*)(sLS + e_loc * 16 + kg * 8)     = s0;
        *(float4*)(sLS + e_loc * 16 + kg * 8 + 4) = s1;
        #pragma unroll
        for (int e = 0; e < 8; ++e) xb[e] = (short)f2bf(ls[e]);
    }
    const f32x4 z4 = {0.f, 0.f, 0.f, 0.f};
    typedef union { unsigned u[4]; short8v v; } pk_t;
    pk_t h1[4];
    #pragma unroll
    for (int ks = 0; ks < 4; ++ks) {
        #pragma unroll
        for (int half = 0; half < 2; ++half) {
            int ct = 2 * ks + half;
            short8v wf = *(const short8v*)(w1p + (ct * 16 + m) * 32 + kg * 8);
            f32x4 acc = __builtin_amdgcn_mfma_f32_16x16x32_bf16(wf, xb, z4, 0, 0, 0);
            float4 bv = *(const float4*)(b1 + ks * 32 + kg * 8 + half * 4);
            float v0 = fmaxf(acc[0] + bv.x, 0.f), v1 = fmaxf(acc[1] + bv.y, 0.f);
            float v2 = fmaxf(acc[2] + bv.z, 0.f), v3 = fmaxf(acc[3] + bv.w, 0.f);
            h1[ks].u[2 * half]     = pack2bf(v0, v1);
            h1[ks].u[2 * half + 1] = pack2bf(v2, v3);
        }
    }
    f32x4 acc2[8];
    #pragma unroll
    for (int ct = 0; ct < 8; ++ct) acc2[ct] = z4;
    #pragma unroll
    for (int ks = 0; ks < 4; ++ks) {
        short8v hf = h1[ks].v;
        #pragma unroll
        for (int ct = 0; ct < 8; ++ct) {
            short8v wf = *(const short8v*)(w2p + (ct * 16 + m) * 128 + ks * 32 + kg * 8);
            acc2[ct] = __builtin_amdgcn_mfma_f32_16x16x32_bf16(wf, hf, acc2[ct], 0, 0, 0);
        }
    }
    pk_t h2[4];
    #pragma unroll
    for (int ks = 0; ks < 4; ++ks) {
        #pragma unroll
        for (int half = 0; half < 2; ++half) {
            int ct = 2 * ks + half;
            float4 bv = *(const float4*)(b2 + ks * 32 + kg * 8 + half * 4);
            float v0 = fmaxf(acc2[ct][0] + bv.x, 0.f), v1 = fmaxf(acc2[ct][1] + bv.y, 0.f);
            float v2 = fmaxf(acc2[ct][2] + bv.z, 0.f), v3 = fmaxf(acc2[ct][3] + bv.w, 0.f);
            h2[ks].u[2 * half]     = pack2bf(v0, v1);
            h2[ks].u[2 * half + 1] = pack2bf(v2, v3);
        }
    }
    f32x4 acc3 = z4;
    #pragma unroll
    for (int ks = 0; ks < 4; ++ks) {
        short8v wf = *(const short8v*)(w3t + m * 128 + ks * 32 + kg * 8);
        acc3 = __builtin_amdgcn_mfma_f32_16x16x32_bf16(wf, h2[ks].v, acc3, 0, 0, 0);
    }
    {
        uint2 u = { pack2bf(acc3[0], acc3[1]), pack2bf(acc3[2], acc3[3]) };
        *(uint2*)(sO + e_loc * 16 + kg * 4) = u;
    }
    __syncthreads();
    float w0 = est_w[0];
    float al = fminf(fmaxf(alpha[0], 0.f), 1.f);
    float oma = 1.0f - al;
    {
        int e2 = t >> 2, q = t & 3;
        float* lsp = sLS + e2 * 16 + q * 4;
        float4 lv = *(float4*)lsp;
        const unsigned short* op = sO + e2 * 16;
        float or0 = bf2f(op[2 * q])     + b3[2 * q];
        float or1 = bf2f(op[2 * q + 1]) + b3[2 * q + 1];
        float oi0 = bf2f(op[8 + 2 * q]) + b3[8 + 2 * q];
        float oi1 = bf2f(op[9 + 2 * q]) + b3[9 + 2 * q];
        float4 cb;
        cb.x = al * (lv.x * w0) + oma * fast_tanh(or0);
        cb.y = al * (lv.y * w0) + oma * fast_tanh(oi0);
        cb.z = al * (lv.z * w0) + oma * fast_tanh(or1);
        cb.w = al * (lv.w * w0) + oma * fast_tanh(oi1);
        *(float4*)lsp = cb;
    }
    __syncthreads();
    {
        int j = l & 31, half = l >> 5;
        float Ar[32];
        const float4* ap = (const float4*)(Amat + j * 32);
        #pragma unroll
        for (int q4 = 0; q4 < 8; ++q4) {
            float4 v = ap[q4];
            Ar[4 * q4 + 0] = v.x; Ar[4 * q4 + 1] = v.y;
            Ar[4 * q4 + 2] = v.z; Ar[4 * q4 + 3] = v.w;
        }
        #pragma unroll
        for (int it = 0; it < 8; ++it) {
            int e2 = w * 16 + 2 * it + half;
            long gelem = (long)blockIdx.x * 64 + e2;
            const float* lsp = sLS + e2 * 16;
            float4 C0 = *(const float4*)(lsp + 0), C1 = *(const float4*)(lsp + 4);
            float4 C2 = *(const float4*)(lsp + 8), C3 = *(const float4*)(lsp + 12);
            float cr[8] = { C0.x, C0.z, C1.x, C1.z, C2.x, C2.z, C3.x, C3.z };
            float ci[8] = { C0.y, C0.w, C1.y, C1.w, C2.y, C2.w, C3.y, C3.w };
            float hr0 = 0.f, hi0 = 0.f, hr1 = 0.f, hi1 = 0.f;
            #pragma unroll
            for (int p = 0; p < 8; ++p) {
                float a0r = Ar[2 * p], a0i = Ar[2 * p + 1];
                float a1r = Ar[16 + 2 * p], a1i = Ar[17 + 2 * p];
                hr0 += cr[p] * a0r - ci[p] * a0i;
                hi0 += cr[p] * a0i + ci[p] * a0r;
                hr1 += cr[p] * a1r - ci[p] * a1i;
                hi1 += cr[p] * a1i + ci[p] * a1r;
            }
            if (gelem < B) {
                float4 st = { hr0, hi0, hr1, hi1 };
                *(float4*)(out + gelem * 128 + j * 4) = st;
            }
        }
    }
}

extern "C" void kernel_launch(void* const* d_in, const int* in_sizes, int n_in,
                              void* d_out, int out_size, void* d_ws, size_t ws_size,
                              hipStream_t stream) {
    const float* Y             = (const float*)d_in[0];
    const float* Xp            = (const float*)d_in[1];
    const int*   pilot_pos     = (const int*)d_in[2];
    const float* W1            = (const float*)d_in[3];
    const float* b1            = (const float*)d_in[4];
    const float* W2            = (const float*)d_in[5];
    const float* b2            = (const float*)d_in[6];
    const float* W3            = (const float*)d_in[7];
    const float* b3            = (const float*)d_in[8];
    const float* est_w         = (const float*)d_in[9];
    const float* alpha         = (const float*)d_in[10];
    const float* decay_param   = (const float*)d_in[11];
    const float* window_logits = (const float*)d_in[12];
    float* out = (float*)d_out;
    char* ws = (char*)d_ws;

    int B = in_sizes[0] / 128;

    hipLaunchKernelGGL(ce_prep_kernel, dim3(1), dim3(256), 0, stream,
                       pilot_pos, decay_param, window_logits, W1, W2, W3, ws);

    size_t need = (size_t)WS_LS + (size_t)B * 64;
    if (ws_size >= need) {
        float* lsbuf = (float*)(ws + WS_LS);
        hipLaunchKernelGGL(ce_ls, dim3((B + 255) / 256), dim3(256), 0, stream,
                           Y, Xp, pilot_pos, lsbuf, B);
        hipLaunchKernelGGL(ce_mlp, dim3((B + 63) / 64), dim3(256), 0, stream,
                           lsbuf, b1, b2, b3, est_w, alpha, ws, out, B);
    } else {
        hipLaunchKernelGGL(ce_main_fb, dim3((B + 63) / 64), dim3(256), 0, stream,
                           Y, Xp, pilot_pos, b1, b2, b3, est_w, alpha,
                           ws, out, B);
    }
}